// Round 2
// baseline (382.712 us; speedup 1.0000x reference)
//
#include <hip/hip_runtime.h>

// Problem constants (B=4, S=4096 -> 16384 tokens; H=1024; M=H/2=512; E=8)
#define NTOK 16384
#define HDIM 1024
#define MDIM 512
#define NEXP 8
#define CHUNK 128
#define MAXCHUNK 136   // sum_e ceil(c_e/128) <= 135; +1 slack
#define RCAP 4096      // risky-token fixup list capacity (expect ~800)
#define DELTA 0.02f    // top2-gap guard >> bf16 score noise (~1e-3)
#define LSTR 72        // fp32->bf16 transpose LDS stride
#define NSTEP 16       // HDIM/64 K-steps

#define G1_NWG ((MDIM / 128) * (NTOK / 128))   // 512, %8==0
#define EG_NWG (8 * MAXCHUNK)                  // 1088, %8==0

typedef __bf16 bf16x8 __attribute__((ext_vector_type(8)));
typedef float floatx4 __attribute__((ext_vector_type(4)));

// Async global->LDS 16B: LDS dest is wave-uniform base + lane*16 (HW-fixed).
__device__ __forceinline__ void gll16(const void* g, void* l) {
  __builtin_amdgcn_global_load_lds(
      (const __attribute__((address_space(1))) void*)g,
      (__attribute__((address_space(3))) void*)l, 16, 0, 0);
}

// ---------------------------------------------------------------------------
// hs fp32 -> bf16 (same layout).
// ---------------------------------------------------------------------------
__global__ __launch_bounds__(256) void cvt_hs(
    const float* __restrict__ src, __bf16* __restrict__ dst)
{
  const size_t i = ((size_t)blockIdx.x * 256 + threadIdx.x) * 8;
  float4 a = *(const float4*)&src[i];
  float4 b = *(const float4*)&src[i + 4];
  bf16x8 o;
  o[0] = (__bf16)a.x; o[1] = (__bf16)a.y; o[2] = (__bf16)a.z; o[3] = (__bf16)a.w;
  o[4] = (__bf16)b.x; o[5] = (__bf16)b.y; o[6] = (__bf16)b.z; o[7] = (__bf16)b.w;
  *(bf16x8*)&dst[i] = o;
}

// ---------------------------------------------------------------------------
// Batched transpose+convert: src fp32 [b][K][C] -> dst bf16 [b][C][K].
// ---------------------------------------------------------------------------
__global__ __launch_bounds__(256) void transpose_cvt(
    const float* __restrict__ src, __bf16* __restrict__ dst, int K, int C)
{
  __shared__ __align__(16) __bf16 T[64 * LSTR];
  const int b = blockIdx.z;
  const int k0 = blockIdx.x * 64, c0 = blockIdx.y * 64;
  const float* S = src + (size_t)b * K * C;
  __bf16* D = dst + (size_t)b * K * C;
  const int t = threadIdx.x;
  {
    const int r = t >> 2, cc = (t & 3) * 16;
    const float* p = S + (size_t)(k0 + r) * C + c0 + cc;
    float4 v0 = *(const float4*)&p[0];
    float4 v1 = *(const float4*)&p[4];
    float4 v2 = *(const float4*)&p[8];
    float4 v3 = *(const float4*)&p[12];
    float vv[16] = {v0.x, v0.y, v0.z, v0.w, v1.x, v1.y, v1.z, v1.w,
                    v2.x, v2.y, v2.z, v2.w, v3.x, v3.y, v3.z, v3.w};
#pragma unroll
    for (int j = 0; j < 16; ++j) T[(cc + j) * LSTR + r] = (__bf16)vv[j];
  }
  __syncthreads();
  {
    const int c = t >> 2, kk = (t & 3) * 16;
    __bf16* q = D + (size_t)(c0 + c) * K + k0 + kk;
    *(float4*)&q[0] = *(const float4*)&T[c * LSTR + kk];
    *(float4*)&q[8] = *(const float4*)&T[c * LSTR + kk + 8];
  }
}

// ---------------------------------------------------------------------------
// GEMM1 -> h_bf [NTOK][MDIM] (bf16, relu'd). 128x128 tile, BK=64, 512 thr
// (8 waves 2x4, 64x32 out/wave). 4-deep LDS pipeline with counted vmcnt:
// prefetch 3 K-tiles ahead, ONE s_barrier per K-step, s_waitcnt vmcnt(8)
// (4 gll16/tile/wave; tiles t+1,t+2 stay in flight). XCD-bijective swizzle.
// ---------------------------------------------------------------------------
__global__ __launch_bounds__(512, 2) void gemm1_h(
    const __bf16* __restrict__ A,    // hs_bf16 [NTOK][HDIM]
    const __bf16* __restrict__ Bt,   // w1t [MDIM][HDIM]
    const float* __restrict__ bias,  // b1 [MDIM]
    __bf16* __restrict__ hbf)        // [NTOK][MDIM]
{
  __shared__ __align__(16) __bf16 As[4][128 * 64];
  __shared__ __align__(16) __bf16 Bs[4][128 * 64];

  const int tid = threadIdx.x;
  const int swz = (blockIdx.x & 7) * (G1_NWG / 8) + (blockIdx.x >> 3);
  const int rowBlk = swz >> 2;          // 0..127
  const int cb = swz & 3;               // 0..3
  const int row0 = rowBlk * 128, col0 = cb * 128;
  const int wave = tid >> 6, lane = tid & 63;
  const int lrow8 = lane >> 3;
  const int gchunk = (lane & 7) ^ lrow8;   // global-side swizzle
  const int wr = (wave >> 2) * 64;         // 2 row-halves
  const int wc = (wave & 3) * 32;          // 4 col-quarters
  const int lrow = lane & 15, quad = lane >> 4;

  const __bf16 *pa[2], *pb[2];
#pragma unroll
  for (int p = 0; p < 2; ++p) {
    const int rb = wave * 8 + p * 64;   // 8-aligned -> row&7 == lrow8
    pa[p] = A + (size_t)(row0 + rb + lrow8) * HDIM + gchunk * 8;
    pb[p] = Bt + (size_t)(col0 + rb + lrow8) * HDIM + gchunk * 8;
  }

  floatx4 acc[4][2];
#pragma unroll
  for (int i = 0; i < 4; ++i)
#pragma unroll
    for (int j = 0; j < 2; ++j) acc[i][j] = (floatx4){0.f, 0.f, 0.f, 0.f};

  // prologue: stage tiles 0..2 (12 gll16/wave outstanding)
#pragma unroll
  for (int pt = 0; pt < 3; ++pt) {
#pragma unroll
    for (int p = 0; p < 2; ++p) {
      const int rb = wave * 8 + p * 64;
      gll16(pa[p] + pt * 64, &As[pt][rb * 64]);
      gll16(pb[p] + pt * 64, &Bs[pt][rb * 64]);
    }
  }

  for (int t = 0; t < NSTEP; ++t) {
    // wait: tile t complete (4 gll16/tile/wave in flight per future tile)
    if (t < NSTEP - 2)      asm volatile("s_waitcnt vmcnt(8)" ::: "memory");
    else if (t == NSTEP - 2) asm volatile("s_waitcnt vmcnt(4)" ::: "memory");
    else                     asm volatile("s_waitcnt vmcnt(0)" ::: "memory");
    __builtin_amdgcn_s_barrier();
    __builtin_amdgcn_sched_barrier(0);
    if (t + 3 < NSTEP) {
      const int koff = (t + 3) * 64;
      const int bn = (t + 3) & 3;
#pragma unroll
      for (int p = 0; p < 2; ++p) {
        const int rb = wave * 8 + p * 64;
        gll16(pa[p] + koff, &As[bn][rb * 64]);
        gll16(pb[p] + koff, &Bs[bn][rb * 64]);
      }
    }
    __builtin_amdgcn_sched_barrier(0);
    const __bf16* Ab = As[t & 3];
    const __bf16* Bb = Bs[t & 3];
#pragma unroll
    for (int kh = 0; kh < 2; ++kh) {
      bf16x8 a[4], b[2];
#pragma unroll
      for (int i = 0; i < 4; ++i)
        a[i] = *(const bf16x8*)&Ab[(wr + i * 16 + lrow) * 64 +
                                   (((kh * 4 + quad) ^ (lrow & 7)) * 8)];
#pragma unroll
      for (int j = 0; j < 2; ++j)
        b[j] = *(const bf16x8*)&Bb[(wc + j * 16 + lrow) * 64 +
                                   (((kh * 4 + quad) ^ (lrow & 7)) * 8)];
#pragma unroll
      for (int i = 0; i < 4; ++i)
#pragma unroll
        for (int j = 0; j < 2; ++j)
          acc[i][j] = __builtin_amdgcn_mfma_f32_16x16x32_bf16(a[i], b[j], acc[i][j], 0, 0, 0);
    }
  }

  // ---- epilogue: +bias, relu, bf16, store h ----
  float bj[2];
#pragma unroll
  for (int j = 0; j < 2; ++j) bj[j] = bias[col0 + wc + j * 16 + lrow];
#pragma unroll
  for (int i = 0; i < 4; ++i)
#pragma unroll
    for (int r = 0; r < 4; ++r) {
      const int tokr = row0 + wr + i * 16 + quad * 4 + r;
      __bf16* hp = hbf + (size_t)tokr * MDIM + col0;
#pragma unroll
      for (int j = 0; j < 2; ++j) {
        const int cl = wc + j * 16 + lrow;
        hp[cl] = (__bf16)fmaxf(acc[i][j][r] + bj[j], 0.f);
      }
    }
}

// ---------------------------------------------------------------------------
// Score + route: s[t][e] = h[t]·w2[:,e] + b2[e] (fp32 accum, bf16 h),
// argmax + near-tie risky flag. 8 lanes/token, 32 tokens/block.
// ---------------------------------------------------------------------------
__global__ __launch_bounds__(256) void score_route(
    const __bf16* __restrict__ hbf, const float* __restrict__ w2,
    const float* __restrict__ b2, int* __restrict__ top_idx,
    int* __restrict__ risky_n, int* __restrict__ risky)
{
  __shared__ int rbuf[32];
  __shared__ int rcnt, rbase;
  if (threadIdx.x == 0) rcnt = 0;
  __syncthreads();

  const int tok = blockIdx.x * 32 + (threadIdx.x >> 3);
  const int l8 = threadIdx.x & 7;
  const __bf16* hrow = hbf + (size_t)tok * MDIM;

  float s[8] = {0, 0, 0, 0, 0, 0, 0, 0};
#pragma unroll
  for (int u = 0; u < 8; ++u) {
    const int m0 = u * 64 + l8 * 8;
    bf16x8 hv = *(const bf16x8*)&hrow[m0];
#pragma unroll
    for (int q = 0; q < 8; ++q) {
      const float h = (float)hv[q];
      float4 wa = *(const float4*)&w2[(m0 + q) * 8];
      float4 wb = *(const float4*)&w2[(m0 + q) * 8 + 4];
      s[0] += h * wa.x; s[1] += h * wa.y; s[2] += h * wa.z; s[3] += h * wa.w;
      s[4] += h * wb.x; s[5] += h * wb.y; s[6] += h * wb.z; s[7] += h * wb.w;
    }
  }
#pragma unroll
  for (int off = 1; off <= 4; off <<= 1)
#pragma unroll
    for (int e = 0; e < 8; ++e) s[e] += __shfl_xor(s[e], off, 64);

  if (l8 == 0) {
    float v0 = s[0] + b2[0];
    float best = v0, second = -1e30f;
    int bi = 0;
#pragma unroll
    for (int e = 1; e < 8; ++e) {
      float v = s[e] + b2[e];
      if (v > best) { second = best; best = v; bi = e; }
      else if (v > second) second = v;
    }
    top_idx[tok] = bi;
    if (best - second < DELTA) rbuf[atomicAdd(&rcnt, 1)] = tok;
  }
  __syncthreads();
  if (threadIdx.x == 0 && rcnt > 0) rbase = atomicAdd(risky_n, rcnt);
  __syncthreads();
  if ((int)threadIdx.x < rcnt) {
    int slot = rbase + threadIdx.x;
    if (slot < RCAP) risky[slot] = rbuf[threadIdx.x];
  }
}

// ---------------------------------------------------------------------------
// Exact fp32 h for risky tokens -> compact hfix[RCAP][MDIM].
// ---------------------------------------------------------------------------
__global__ __launch_bounds__(256) void gemm1_fix_v2(
    const float* __restrict__ A, const float* __restrict__ W,
    const float* __restrict__ bias, const int* __restrict__ risky,
    float* __restrict__ hfix)
{
  __shared__ float As[32][33];
  __shared__ float Bs[32][64];
  __shared__ int toks[32];

  const int tid = threadIdx.x;
  if (tid < 32) toks[tid] = risky[blockIdx.y * 32 + tid];
  __syncthreads();
  if (toks[0] < 0) return;

  const int col0 = blockIdx.x * 64;
  const int tx = tid & 15, ty = tid >> 4;
  float acc0[4] = {0, 0, 0, 0}, acc1[4] = {0, 0, 0, 0};

  const int sr = tid >> 3;
  const int lo = tid & 7;
  const int sc8 = lo * 8;
  const int tokS = toks[sr];
  const float* pa = (tokS >= 0) ? A + (size_t)tokS * HDIM : A;

  for (int k0 = 0; k0 < HDIM; k0 += 32) {
    float4 av = make_float4(0, 0, 0, 0);
    if (tokS >= 0) av = *(const float4*)&pa[k0 + (lo & 3) * 4 + (lo >> 2) * 16];
    float4 b0 = *(const float4*)&W[(size_t)(k0 + sr) * MDIM + col0 + sc8];
    float4 b1v = *(const float4*)&W[(size_t)(k0 + sr) * MDIM + col0 + sc8 + 4];
    const int kk = (lo & 3) * 4 + (lo >> 2) * 16;
    As[kk + 0][sr] = av.x; As[kk + 1][sr] = av.y;
    As[kk + 2][sr] = av.z; As[kk + 3][sr] = av.w;
    *(float4*)&Bs[sr][sc8] = b0;
    *(float4*)&Bs[sr][sc8 + 4] = b1v;
    __syncthreads();

#pragma unroll
    for (int k = 0; k < 32; ++k) {
      float a0 = As[k][ty], a1 = As[k][ty + 16];
      float4 bv = *(const float4*)&Bs[k][tx * 4];
      acc0[0] = fmaf(a0, bv.x, acc0[0]); acc0[1] = fmaf(a0, bv.y, acc0[1]);
      acc0[2] = fmaf(a0, bv.z, acc0[2]); acc0[3] = fmaf(a0, bv.w, acc0[3]);
      acc1[0] = fmaf(a1, bv.x, acc1[0]); acc1[1] = fmaf(a1, bv.y, acc1[1]);
      acc1[2] = fmaf(a1, bv.z, acc1[2]); acc1[3] = fmaf(a1, bv.w, acc1[3]);
    }
    __syncthreads();
  }

  const int c = col0 + tx * 4;
  const int i0 = blockIdx.y * 32 + ty, i1 = blockIdx.y * 32 + ty + 16;
  if (toks[ty] >= 0) {
    float4 v;
    v.x = fmaxf(acc0[0] + bias[c + 0], 0.f); v.y = fmaxf(acc0[1] + bias[c + 1], 0.f);
    v.z = fmaxf(acc0[2] + bias[c + 2], 0.f); v.w = fmaxf(acc0[3] + bias[c + 3], 0.f);
    *(float4*)&hfix[(size_t)i0 * MDIM + c] = v;
  }
  if (toks[ty + 16] >= 0) {
    float4 v;
    v.x = fmaxf(acc1[0] + bias[c + 0], 0.f); v.y = fmaxf(acc1[1] + bias[c + 1], 0.f);
    v.z = fmaxf(acc1[2] + bias[c + 2], 0.f); v.w = fmaxf(acc1[3] + bias[c + 3], 0.f);
    *(float4*)&hfix[(size_t)i1 * MDIM + c] = v;
  }
}

// ---------------------------------------------------------------------------
// Exact rescore of risky tokens from hfix; overwrite top_idx.
// ---------------------------------------------------------------------------
__global__ __launch_bounds__(256) void rescore_fix(
    const float* __restrict__ hfix, const float* __restrict__ w2,
    const float* __restrict__ b2, const int* __restrict__ risky,
    int* __restrict__ top_idx)
{
  const int idx = blockIdx.x * 32 + (threadIdx.x >> 3);
  const int l8 = threadIdx.x & 7;
  const int t = risky[idx];

  float s[8] = {0, 0, 0, 0, 0, 0, 0, 0};
  if (t >= 0) {
    const float* hrow = hfix + (size_t)idx * MDIM;
    for (int k = l8; k < MDIM; k += 8) {
      float hv = hrow[k];
      float4 wa = *(const float4*)&w2[k * 8];
      float4 wb = *(const float4*)&w2[k * 8 + 4];
      s[0] += hv * wa.x; s[1] += hv * wa.y; s[2] += hv * wa.z; s[3] += hv * wa.w;
      s[4] += hv * wb.x; s[5] += hv * wb.y; s[6] += hv * wb.z; s[7] += hv * wb.w;
    }
  }
#pragma unroll
  for (int off = 4; off > 0; off >>= 1)
#pragma unroll
    for (int e = 0; e < 8; ++e) s[e] += __shfl_xor(s[e], off, 64);

  if (l8 == 0 && t >= 0) {
    float best = s[0] + b2[0];
    int bi = 0;
#pragma unroll
    for (int e = 1; e < 8; ++e) {
      float v = s[e] + b2[e];
      if (v > best) { best = v; bi = e; }
    }
    top_idx[t] = bi;
  }
}

// ---------------------------------------------------------------------------
__global__ __launch_bounds__(256) void count_tokens(
    const int* __restrict__ top_idx, int* __restrict__ counts)
{
  __shared__ int lc[NEXP];
  if (threadIdx.x < NEXP) lc[threadIdx.x] = 0;
  __syncthreads();
  atomicAdd(&lc[top_idx[blockIdx.x * 256 + threadIdx.x]], 1);
  __syncthreads();
  if (threadIdx.x < NEXP) atomicAdd(&counts[threadIdx.x], lc[threadIdx.x]);
}

// Scatter with inline padded-offset prefix (counts finalized previous kernel).
__global__ __launch_bounds__(256) void scatter_tokens(
    const int* __restrict__ top_idx, const int* __restrict__ counts,
    int* __restrict__ cursor, int* __restrict__ sorted)
{
  __shared__ int lc[NEXP], lbase[NEXP], off_s[NEXP];
  if (threadIdx.x < NEXP) lc[threadIdx.x] = 0;
  if (threadIdx.x == 0) {
    int off = 0;
    for (int e = 0; e < NEXP; ++e) {
      off_s[e] = off;
      off += ((counts[e] + CHUNK - 1) / CHUNK) * CHUNK;
    }
  }
  __syncthreads();
  const int t = blockIdx.x * 256 + threadIdx.x;
  const int e = top_idx[t];
  const int r = atomicAdd(&lc[e], 1);
  __syncthreads();
  if (threadIdx.x < NEXP)
    lbase[threadIdx.x] = atomicAdd(&cursor[threadIdx.x], lc[threadIdx.x]);
  __syncthreads();
  sorted[off_s[e] + lbase[e] + r] = t;
}

// ---------------------------------------------------------------------------
// Expert GEMM v5: 128x128, BK=64, 512 thr (8 waves 2x4). 4-deep LDS pipeline,
// counted vmcnt (never 0 in steady state), one s_barrier/K-step, XOR k-chunk
// swizzle, XCD chunk-major block swizzle (weights L2-resident per XCD).
// ---------------------------------------------------------------------------
__global__ __launch_bounds__(512, 2) void expert_gemm_v5(
    const __bf16* __restrict__ A,   // hs_bf16 [NTOK][HDIM]
    const __bf16* __restrict__ Wt,  // [NEXP][HDIM(col)][HDIM(k)]
    const float* __restrict__ Eb,   // [NEXP][HDIM]
    const int* __restrict__ sorted,
    const int* __restrict__ top_idx,
    float* __restrict__ Out)
{
  __shared__ __align__(16) __bf16 As[4][128 * 64];
  __shared__ __align__(16) __bf16 Bs[4][128 * 64];
  __shared__ int toks[CHUNK];

  const int tid = threadIdx.x;
  const int swz = (blockIdx.x & 7) * (EG_NWG / 8) + (blockIdx.x >> 3);
  const int chunkIdx = swz >> 3;   // 0..135
  const int cb = swz & 7;          // 0..7
  if (tid < CHUNK) toks[tid] = sorted[(size_t)chunkIdx * CHUNK + tid];
  __syncthreads();
  if (toks[0] < 0) return;

  const int e = top_idx[toks[0]];
  const int col0 = cb * 128;
  const int wave = tid >> 6, lane = tid & 63;
  const int lrow8 = lane >> 3;
  const int gchunk = (lane & 7) ^ lrow8;
  const int wr = (wave >> 2) * 64;
  const int wc = (wave & 3) * 32;
  const int lrow = lane & 15, quad = lane >> 4;

  const __bf16 *pa[2], *pb[2];
#pragma unroll
  for (int p = 0; p < 2; ++p) {
    const int rb = wave * 8 + p * 64;
    const int tk = toks[rb + lrow8];
    pa[p] = A + (size_t)(tk < 0 ? 0 : tk) * HDIM + gchunk * 8;
    pb[p] = Wt + ((size_t)e * HDIM + col0 + rb + lrow8) * HDIM + gchunk * 8;
  }

  floatx4 acc[4][2];
#pragma unroll
  for (int i = 0; i < 4; ++i)
#pragma unroll
    for (int j = 0; j < 2; ++j) acc[i][j] = (floatx4){0.f, 0.f, 0.f, 0.f};

  // prologue: stage tiles 0..2
#pragma unroll
  for (int pt = 0; pt < 3; ++pt) {
#pragma unroll
    for (int p = 0; p < 2; ++p) {
      const int rb = wave * 8 + p * 64;
      gll16(pa[p] + pt * 64, &As[pt][rb * 64]);
      gll16(pb[p] + pt * 64, &Bs[pt][rb * 64]);
    }
  }

  for (int t = 0; t < NSTEP; ++t) {
    if (t < NSTEP - 2)      asm volatile("s_waitcnt vmcnt(8)" ::: "memory");
    else if (t == NSTEP - 2) asm volatile("s_waitcnt vmcnt(4)" ::: "memory");
    else                     asm volatile("s_waitcnt vmcnt(0)" ::: "memory");
    __builtin_amdgcn_s_barrier();
    __builtin_amdgcn_sched_barrier(0);
    if (t + 3 < NSTEP) {
      const int koff = (t + 3) * 64;
      const int bn = (t + 3) & 3;
#pragma unroll
      for (int p = 0; p < 2; ++p) {
        const int rb = wave * 8 + p * 64;
        gll16(pa[p] + koff, &As[bn][rb * 64]);
        gll16(pb[p] + koff, &Bs[bn][rb * 64]);
      }
    }
    __builtin_amdgcn_sched_barrier(0);
    const __bf16* Ab = As[t & 3];
    const __bf16* Bb = Bs[t & 3];
#pragma unroll
    for (int kh = 0; kh < 2; ++kh) {
      bf16x8 a[4], b[2];
#pragma unroll
      for (int i = 0; i < 4; ++i)
        a[i] = *(const bf16x8*)&Ab[(wr + i * 16 + lrow) * 64 +
                                   (((kh * 4 + quad) ^ (lrow & 7)) * 8)];
#pragma unroll
      for (int j = 0; j < 2; ++j)
        b[j] = *(const bf16x8*)&Bb[(wc + j * 16 + lrow) * 64 +
                                   (((kh * 4 + quad) ^ (lrow & 7)) * 8)];
#pragma unroll
      for (int i = 0; i < 4; ++i)
#pragma unroll
        for (int j = 0; j < 2; ++j)
          acc[i][j] = __builtin_amdgcn_mfma_f32_16x16x32_bf16(a[i], b[j], acc[i][j], 0, 0, 0);
    }
  }

  const float* be = Eb + (size_t)e * HDIM + col0;
#pragma unroll
  for (int i = 0; i < 4; ++i)
#pragma unroll
    for (int r = 0; r < 4; ++r) {
      const int row = wr + i * 16 + quad * 4 + r;
      const int tok = toks[row];
      if (tok < 0) continue;
      float* po = Out + (size_t)tok * HDIM + col0;
#pragma unroll
      for (int j = 0; j < 2; ++j) {
        const int col = wc + j * 16 + lrow;
        po[col] = acc[i][j][r] + be[col];
      }
    }
}

// ---------------------------------------------------------------------------
extern "C" void kernel_launch(void* const* d_in, const int* in_sizes, int n_in,
                              void* d_out, int out_size, void* d_ws, size_t ws_size,
                              hipStream_t stream) {
  (void)in_sizes; (void)n_in; (void)out_size; (void)ws_size;

  const float* hs = (const float*)d_in[0];
  const float* w1 = (const float*)d_in[1];
  const float* b1 = (const float*)d_in[2];
  const float* w2 = (const float*)d_in[3];
  const float* b2 = (const float*)d_in[4];
  const float* eW = (const float*)d_in[5];
  const float* eb = (const float*)d_in[6];
  float* out = (float*)d_out;

  // d_out doubles as scratch until expert_gemm_v5 (last kernel) overwrites it
  // completely: hfix [RCAP][MDIM] fp32 (8MB) + h_bf [NTOK][MDIM] bf16 (16MB).
  float* hfix = (float*)d_out;                                   // 8 MB @0
  __bf16* h_bf = (__bf16*)((char*)d_out + (size_t)8 * 1024 * 1024); // 16 MB

  char* wsb = (char*)d_ws;
  int* top_idx = (int*)wsb;                          // 65536 B
  int* ctrl    = (int*)(wsb + 65536);                // zeroed 128 B:
  int* counts  = ctrl;                               //   [0..7]
  int* risky_n = ctrl + 8;                           //   [8]
  int* cursor  = ctrl + 16;                          //   [16..23]
  int* risky   = (int*)(wsb + 65792);                // RCAP ints, 0xFF
  int* sorted  = risky + RCAP;                       // MAXCHUNK*CHUNK, 0xFF
  __bf16* hs_bf = (__bf16*)(wsb + 163840);           // 33.5 MB
  __bf16* w1t   = (__bf16*)(wsb + 163840 + 33554432);
  __bf16* eWt   = (__bf16*)(wsb + 163840 + 33554432 + 1048576);

  hipMemsetAsync(ctrl, 0, 128, stream);
  hipMemsetAsync(risky, 0xFF, (RCAP + MAXCHUNK * CHUNK) * sizeof(int), stream);

  cvt_hs<<<NTOK * HDIM / (256 * 8), 256, 0, stream>>>(hs, hs_bf);
  transpose_cvt<<<dim3(HDIM / 64, MDIM / 64, 1), 256, 0, stream>>>(w1, w1t, HDIM, MDIM);
  transpose_cvt<<<dim3(HDIM / 64, HDIM / 64, NEXP), 256, 0, stream>>>(eW, eWt, HDIM, HDIM);

  gemm1_h<<<dim3(G1_NWG), 512, 0, stream>>>(hs_bf, w1t, b1, h_bf);
  score_route<<<NTOK / 32, 256, 0, stream>>>(h_bf, w2, b2, top_idx, risky_n, risky);
  gemm1_fix_v2<<<dim3(MDIM / 64, RCAP / 32), 256, 0, stream>>>(hs, w1, b1, risky, hfix);
  rescore_fix<<<RCAP / 32, 256, 0, stream>>>(hfix, w2, b2, risky, top_idx);
  count_tokens<<<NTOK / 256, 256, 0, stream>>>(top_idx, counts);
  scatter_tokens<<<NTOK / 256, 256, 0, stream>>>(top_idx, counts, cursor, sorted);
  expert_gemm_v5<<<dim3(EG_NWG), 512, 0, stream>>>(hs_bf, eWt, eb, sorted, top_idx, out);
}

// Round 3
// 346.553 us; speedup vs baseline: 1.1043x; 1.1043x over previous
//
#include <hip/hip_runtime.h>

// Problem constants (B=4, S=4096 -> 16384 tokens; H=1024; M=H/2=512; E=8)
#define NTOK 16384
#define HDIM 1024
#define MDIM 512
#define NEXP 8
#define CHUNK 128
#define MAXCHUNK 136   // sum_e ceil(c_e/128) <= 135; +1 slack
#define RCAP 4096      // risky-token fixup list capacity (expect ~800)
#define DELTA 0.02f    // top2-gap guard >> bf16 score noise (~1e-3)
#define LSTR 72        // fp32->bf16 transpose LDS stride

#define G1_NWG ((MDIM / 128) * (NTOK / 128))   // 512, %8==0
#define EG_NWG (8 * MAXCHUNK)                  // 1088, %8==0

typedef __bf16 bf16x8 __attribute__((ext_vector_type(8)));
typedef float floatx4 __attribute__((ext_vector_type(4)));

// Async global->LDS 16B: LDS dest is wave-uniform base + lane*16 (HW-fixed).
__device__ __forceinline__ void gll16(const void* g, void* l) {
  __builtin_amdgcn_global_load_lds(
      (const __attribute__((address_space(1))) void*)g,
      (__attribute__((address_space(3))) void*)l, 16, 0, 0);
}

// ---------------------------------------------------------------------------
// hs fp32 -> bf16 (same layout).
// ---------------------------------------------------------------------------
__global__ __launch_bounds__(256) void cvt_hs(
    const float* __restrict__ src, __bf16* __restrict__ dst)
{
  const size_t i = ((size_t)blockIdx.x * 256 + threadIdx.x) * 8;
  float4 a = *(const float4*)&src[i];
  float4 b = *(const float4*)&src[i + 4];
  bf16x8 o;
  o[0] = (__bf16)a.x; o[1] = (__bf16)a.y; o[2] = (__bf16)a.z; o[3] = (__bf16)a.w;
  o[4] = (__bf16)b.x; o[5] = (__bf16)b.y; o[6] = (__bf16)b.z; o[7] = (__bf16)b.w;
  *(bf16x8*)&dst[i] = o;
}

// ---------------------------------------------------------------------------
// Batched transpose+convert: src fp32 [b][K][C] -> dst bf16 [b][C][K].
// ---------------------------------------------------------------------------
__global__ __launch_bounds__(256) void transpose_cvt(
    const float* __restrict__ src, __bf16* __restrict__ dst, int K, int C)
{
  __shared__ __align__(16) __bf16 T[64 * LSTR];
  const int b = blockIdx.z;
  const int k0 = blockIdx.x * 64, c0 = blockIdx.y * 64;
  const float* S = src + (size_t)b * K * C;
  __bf16* D = dst + (size_t)b * K * C;
  const int t = threadIdx.x;
  {
    const int r = t >> 2, cc = (t & 3) * 16;
    const float* p = S + (size_t)(k0 + r) * C + c0 + cc;
    float4 v0 = *(const float4*)&p[0];
    float4 v1 = *(const float4*)&p[4];
    float4 v2 = *(const float4*)&p[8];
    float4 v3 = *(const float4*)&p[12];
    float vv[16] = {v0.x, v0.y, v0.z, v0.w, v1.x, v1.y, v1.z, v1.w,
                    v2.x, v2.y, v2.z, v2.w, v3.x, v3.y, v3.z, v3.w};
#pragma unroll
    for (int j = 0; j < 16; ++j) T[(cc + j) * LSTR + r] = (__bf16)vv[j];
  }
  __syncthreads();
  {
    const int c = t >> 2, kk = (t & 3) * 16;
    __bf16* q = D + (size_t)(c0 + c) * K + k0 + kk;
    *(float4*)&q[0] = *(const float4*)&T[c * LSTR + kk];
    *(float4*)&q[8] = *(const float4*)&T[c * LSTR + kk + 8];
  }
}

// ---------------------------------------------------------------------------
// GEMM1 -> h_bf [NTOK][MDIM] (bf16, relu'd). 128x128 tile, BK=64, 256 thr
// (4 waves 2x2, 64x64 out/wave). 2-phase double-buffered global_load_lds
// staging (stage t+1 || MFMA t, one barrier per K-step) — the R1-verified
// main-loop structure. XOR k-chunk swizzle (0 bank conflicts), XCD-bijective
// row-major-grouped block swizzle.
// ---------------------------------------------------------------------------
__global__ __launch_bounds__(256) void gemm1_h(
    const __bf16* __restrict__ A,    // hs_bf16 [NTOK][HDIM]
    const __bf16* __restrict__ Bt,   // w1t [MDIM][HDIM]
    const float* __restrict__ bias,  // b1 [MDIM]
    __bf16* __restrict__ hbf)        // [NTOK][MDIM]
{
  __shared__ __align__(16) __bf16 As[2 * 128 * 64];
  __shared__ __align__(16) __bf16 Bs[2 * 128 * 64];

  const int tid = threadIdx.x;
  const int swz = (blockIdx.x & 7) * (G1_NWG / 8) + (blockIdx.x >> 3);
  const int rowBlk = swz >> 2;          // 0..127
  const int cb = swz & 3;               // 0..3
  const int row0 = rowBlk * 128, col0 = cb * 128;
  const int wave = tid >> 6, lane = tid & 63;
  const int lrow8 = lane >> 3;
  const int gchunk = (lane & 7) ^ lrow8;   // global-side swizzle
  const int wr = (wave >> 1) * 64, wc = (wave & 1) * 64;
  const int lrow = lane & 15, quad = lane >> 4;

  const __bf16 *pa[4], *pb[4];
#pragma unroll
  for (int p = 0; p < 4; ++p) {
    const int rb = wave * 8 + p * 32;   // 8-aligned -> row&7 == lrow8
    pa[p] = A + (size_t)(row0 + rb + lrow8) * HDIM + gchunk * 8;
    pb[p] = Bt + (size_t)(col0 + rb + lrow8) * HDIM + gchunk * 8;
  }

  floatx4 acc[4][4];
#pragma unroll
  for (int i = 0; i < 4; ++i)
#pragma unroll
    for (int j = 0; j < 4; ++j) acc[i][j] = (floatx4){0.f, 0.f, 0.f, 0.f};

  // prologue: stage tile 0 into buffer 0
#pragma unroll
  for (int p = 0; p < 4; ++p) {
    const int rb = wave * 8 + p * 32;
    gll16(pa[p], &As[rb * 64]);
    gll16(pb[p], &Bs[rb * 64]);
  }
  __syncthreads();

  int cur = 0;
  for (int t = 0; t < HDIM / 64; ++t) {
    const int nxt = cur ^ 1;
    if (t + 1 < HDIM / 64) {
      const int koff = (t + 1) * 64;
#pragma unroll
      for (int p = 0; p < 4; ++p) {
        const int rb = wave * 8 + p * 32;
        gll16(pa[p] + koff, &As[nxt * 8192 + rb * 64]);
        gll16(pb[p] + koff, &Bs[nxt * 8192 + rb * 64]);
      }
    }
    const __bf16* Ab = &As[cur * 8192];
    const __bf16* Bb = &Bs[cur * 8192];
#pragma unroll
    for (int kh = 0; kh < 2; ++kh) {
      bf16x8 a[4], b[4];
#pragma unroll
      for (int i = 0; i < 4; ++i)
        a[i] = *(const bf16x8*)&Ab[(wr + i * 16 + lrow) * 64 +
                                   (((kh * 4 + quad) ^ (lrow & 7)) * 8)];
#pragma unroll
      for (int j = 0; j < 4; ++j)
        b[j] = *(const bf16x8*)&Bb[(wc + j * 16 + lrow) * 64 +
                                   (((kh * 4 + quad) ^ (lrow & 7)) * 8)];
#pragma unroll
      for (int i = 0; i < 4; ++i)
#pragma unroll
        for (int j = 0; j < 4; ++j)
          acc[i][j] = __builtin_amdgcn_mfma_f32_16x16x32_bf16(a[i], b[j], acc[i][j], 0, 0, 0);
    }
    __syncthreads();   // drains vmcnt(0): stage of t+1 had 32 MFMAs of cover
    cur = nxt;
  }

  // ---- epilogue: +bias, relu, bf16, store h (no shuffle reduction) ----
  float bj[4];
#pragma unroll
  for (int j = 0; j < 4; ++j) bj[j] = bias[col0 + wc + j * 16 + lrow];
#pragma unroll
  for (int i = 0; i < 4; ++i)
#pragma unroll
    for (int r = 0; r < 4; ++r) {
      const int tokr = row0 + wr + i * 16 + quad * 4 + r;
      __bf16* hp = hbf + (size_t)tokr * MDIM + col0;
#pragma unroll
      for (int j = 0; j < 4; ++j) {
        const int cl = wc + j * 16 + lrow;
        hp[cl] = (__bf16)fmaxf(acc[i][j][r] + bj[j], 0.f);
      }
    }
}

// ---------------------------------------------------------------------------
// Score + route: s[t][e] = h[t]·w2[:,e] + b2[e] (fp32 accum, bf16 h),
// argmax + near-tie risky flag. 8 lanes/token, 32 tokens/block.
// ---------------------------------------------------------------------------
__global__ __launch_bounds__(256) void score_route(
    const __bf16* __restrict__ hbf, const float* __restrict__ w2,
    const float* __restrict__ b2, int* __restrict__ top_idx,
    int* __restrict__ risky_n, int* __restrict__ risky)
{
  __shared__ int rbuf[32];
  __shared__ int rcnt, rbase;
  if (threadIdx.x == 0) rcnt = 0;
  __syncthreads();

  const int tok = blockIdx.x * 32 + (threadIdx.x >> 3);
  const int l8 = threadIdx.x & 7;
  const __bf16* hrow = hbf + (size_t)tok * MDIM;

  float s[8] = {0, 0, 0, 0, 0, 0, 0, 0};
#pragma unroll
  for (int u = 0; u < 8; ++u) {
    const int m0 = u * 64 + l8 * 8;
    bf16x8 hv = *(const bf16x8*)&hrow[m0];
#pragma unroll
    for (int q = 0; q < 8; ++q) {
      const float h = (float)hv[q];
      float4 wa = *(const float4*)&w2[(m0 + q) * 8];
      float4 wb = *(const float4*)&w2[(m0 + q) * 8 + 4];
      s[0] += h * wa.x; s[1] += h * wa.y; s[2] += h * wa.z; s[3] += h * wa.w;
      s[4] += h * wb.x; s[5] += h * wb.y; s[6] += h * wb.z; s[7] += h * wb.w;
    }
  }
#pragma unroll
  for (int off = 1; off <= 4; off <<= 1)
#pragma unroll
    for (int e = 0; e < 8; ++e) s[e] += __shfl_xor(s[e], off, 64);

  if (l8 == 0) {
    float v0 = s[0] + b2[0];
    float best = v0, second = -1e30f;
    int bi = 0;
#pragma unroll
    for (int e = 1; e < 8; ++e) {
      float v = s[e] + b2[e];
      if (v > best) { second = best; best = v; bi = e; }
      else if (v > second) second = v;
    }
    top_idx[tok] = bi;
    if (best - second < DELTA) rbuf[atomicAdd(&rcnt, 1)] = tok;
  }
  __syncthreads();
  if (threadIdx.x == 0 && rcnt > 0) rbase = atomicAdd(risky_n, rcnt);
  __syncthreads();
  if ((int)threadIdx.x < rcnt) {
    int slot = rbase + threadIdx.x;
    if (slot < RCAP) risky[slot] = rbuf[threadIdx.x];
  }
}

// ---------------------------------------------------------------------------
// Exact fp32 h for risky tokens -> compact hfix[RCAP][MDIM].
// ---------------------------------------------------------------------------
__global__ __launch_bounds__(256) void gemm1_fix_v2(
    const float* __restrict__ A, const float* __restrict__ W,
    const float* __restrict__ bias, const int* __restrict__ risky,
    float* __restrict__ hfix)
{
  __shared__ float As[32][33];
  __shared__ float Bs[32][64];
  __shared__ int toks[32];

  const int tid = threadIdx.x;
  if (tid < 32) toks[tid] = risky[blockIdx.y * 32 + tid];
  __syncthreads();
  if (toks[0] < 0) return;

  const int col0 = blockIdx.x * 64;
  const int tx = tid & 15, ty = tid >> 4;
  float acc0[4] = {0, 0, 0, 0}, acc1[4] = {0, 0, 0, 0};

  const int sr = tid >> 3;
  const int lo = tid & 7;
  const int sc8 = lo * 8;
  const int tokS = toks[sr];
  const float* pa = (tokS >= 0) ? A + (size_t)tokS * HDIM : A;

  for (int k0 = 0; k0 < HDIM; k0 += 32) {
    float4 av = make_float4(0, 0, 0, 0);
    if (tokS >= 0) av = *(const float4*)&pa[k0 + (lo & 3) * 4 + (lo >> 2) * 16];
    float4 b0 = *(const float4*)&W[(size_t)(k0 + sr) * MDIM + col0 + sc8];
    float4 b1v = *(const float4*)&W[(size_t)(k0 + sr) * MDIM + col0 + sc8 + 4];
    const int kk = (lo & 3) * 4 + (lo >> 2) * 16;
    As[kk + 0][sr] = av.x; As[kk + 1][sr] = av.y;
    As[kk + 2][sr] = av.z; As[kk + 3][sr] = av.w;
    *(float4*)&Bs[sr][sc8] = b0;
    *(float4*)&Bs[sr][sc8 + 4] = b1v;
    __syncthreads();

#pragma unroll
    for (int k = 0; k < 32; ++k) {
      float a0 = As[k][ty], a1 = As[k][ty + 16];
      float4 bv = *(const float4*)&Bs[k][tx * 4];
      acc0[0] = fmaf(a0, bv.x, acc0[0]); acc0[1] = fmaf(a0, bv.y, acc0[1]);
      acc0[2] = fmaf(a0, bv.z, acc0[2]); acc0[3] = fmaf(a0, bv.w, acc0[3]);
      acc1[0] = fmaf(a1, bv.x, acc1[0]); acc1[1] = fmaf(a1, bv.y, acc1[1]);
      acc1[2] = fmaf(a1, bv.z, acc1[2]); acc1[3] = fmaf(a1, bv.w, acc1[3]);
    }
    __syncthreads();
  }

  const int c = col0 + tx * 4;
  const int i0 = blockIdx.y * 32 + ty, i1 = blockIdx.y * 32 + ty + 16;
  if (toks[ty] >= 0) {
    float4 v;
    v.x = fmaxf(acc0[0] + bias[c + 0], 0.f); v.y = fmaxf(acc0[1] + bias[c + 1], 0.f);
    v.z = fmaxf(acc0[2] + bias[c + 2], 0.f); v.w = fmaxf(acc0[3] + bias[c + 3], 0.f);
    *(float4*)&hfix[(size_t)i0 * MDIM + c] = v;
  }
  if (toks[ty + 16] >= 0) {
    float4 v;
    v.x = fmaxf(acc1[0] + bias[c + 0], 0.f); v.y = fmaxf(acc1[1] + bias[c + 1], 0.f);
    v.z = fmaxf(acc1[2] + bias[c + 2], 0.f); v.w = fmaxf(acc1[3] + bias[c + 3], 0.f);
    *(float4*)&hfix[(size_t)i1 * MDIM + c] = v;
  }
}

// ---------------------------------------------------------------------------
// Exact rescore of risky tokens from hfix; overwrite top_idx.
// ---------------------------------------------------------------------------
__global__ __launch_bounds__(256) void rescore_fix(
    const float* __restrict__ hfix, const float* __restrict__ w2,
    const float* __restrict__ b2, const int* __restrict__ risky,
    int* __restrict__ top_idx)
{
  const int idx = blockIdx.x * 32 + (threadIdx.x >> 3);
  const int l8 = threadIdx.x & 7;
  const int t = risky[idx];

  float s[8] = {0, 0, 0, 0, 0, 0, 0, 0};
  if (t >= 0) {
    const float* hrow = hfix + (size_t)idx * MDIM;
    for (int k = l8; k < MDIM; k += 8) {
      float hv = hrow[k];
      float4 wa = *(const float4*)&w2[k * 8];
      float4 wb = *(const float4*)&w2[k * 8 + 4];
      s[0] += hv * wa.x; s[1] += hv * wa.y; s[2] += hv * wa.z; s[3] += hv * wa.w;
      s[4] += hv * wb.x; s[5] += hv * wb.y; s[6] += hv * wb.z; s[7] += hv * wb.w;
    }
  }
#pragma unroll
  for (int off = 4; off > 0; off >>= 1)
#pragma unroll
    for (int e = 0; e < 8; ++e) s[e] += __shfl_xor(s[e], off, 64);

  if (l8 == 0 && t >= 0) {
    float best = s[0] + b2[0];
    int bi = 0;
#pragma unroll
    for (int e = 1; e < 8; ++e) {
      float v = s[e] + b2[e];
      if (v > best) { best = v; bi = e; }
    }
    top_idx[t] = bi;
  }
}

// ---------------------------------------------------------------------------
__global__ __launch_bounds__(256) void count_tokens(
    const int* __restrict__ top_idx, int* __restrict__ counts)
{
  __shared__ int lc[NEXP];
  if (threadIdx.x < NEXP) lc[threadIdx.x] = 0;
  __syncthreads();
  atomicAdd(&lc[top_idx[blockIdx.x * 256 + threadIdx.x]], 1);
  __syncthreads();
  if (threadIdx.x < NEXP) atomicAdd(&counts[threadIdx.x], lc[threadIdx.x]);
}

// Scatter with inline padded-offset prefix (counts finalized previous kernel).
__global__ __launch_bounds__(256) void scatter_tokens(
    const int* __restrict__ top_idx, const int* __restrict__ counts,
    int* __restrict__ cursor, int* __restrict__ sorted)
{
  __shared__ int lc[NEXP], lbase[NEXP], off_s[NEXP];
  if (threadIdx.x < NEXP) lc[threadIdx.x] = 0;
  if (threadIdx.x == 0) {
    int off = 0;
    for (int e = 0; e < NEXP; ++e) {
      off_s[e] = off;
      off += ((counts[e] + CHUNK - 1) / CHUNK) * CHUNK;
    }
  }
  __syncthreads();
  const int t = blockIdx.x * 256 + threadIdx.x;
  const int e = top_idx[t];
  const int r = atomicAdd(&lc[e], 1);
  __syncthreads();
  if (threadIdx.x < NEXP)
    lbase[threadIdx.x] = atomicAdd(&cursor[threadIdx.x], lc[threadIdx.x]);
  __syncthreads();
  sorted[off_s[e] + lbase[e] + r] = t;
}

// ---------------------------------------------------------------------------
// Expert GEMM v6 (== R1's v4, the measured-best structure): 128x128 tile,
// BK=64, 256 thr, 2-phase double-buffered global_load_lds staging, XOR
// k-chunk swizzle, XCD chunk-major block swizzle (weights L2-resident/XCD).
// ---------------------------------------------------------------------------
__global__ __launch_bounds__(256) void expert_gemm_v6(
    const __bf16* __restrict__ A,   // hs_bf16 [NTOK][HDIM]
    const __bf16* __restrict__ Wt,  // [NEXP][HDIM(col)][HDIM(k)]
    const float* __restrict__ Eb,   // [NEXP][HDIM]
    const int* __restrict__ sorted,
    const int* __restrict__ top_idx,
    float* __restrict__ Out)
{
  __shared__ __align__(16) __bf16 As[2 * 128 * 64];
  __shared__ __align__(16) __bf16 Bs[2 * 128 * 64];
  __shared__ int toks[CHUNK];

  const int tid = threadIdx.x;
  const int swz = (blockIdx.x & 7) * (EG_NWG / 8) + (blockIdx.x >> 3);
  const int chunkIdx = swz >> 3;   // 0..135
  const int cb = swz & 7;          // 0..7
  if (tid < CHUNK) toks[tid] = sorted[(size_t)chunkIdx * CHUNK + tid];
  __syncthreads();
  if (toks[0] < 0) return;

  const int e = top_idx[toks[0]];
  const int col0 = cb * 128;
  const int wave = tid >> 6, lane = tid & 63;
  const int lrow8 = lane >> 3;
  const int gchunk = (lane & 7) ^ lrow8;
  const int wr = (wave >> 1) * 64, wc = (wave & 1) * 64;
  const int lrow = lane & 15, quad = lane >> 4;

  const __bf16 *pa[4], *pb[4];
#pragma unroll
  for (int p = 0; p < 4; ++p) {
    const int rb = wave * 8 + p * 32;
    const int tk = toks[rb + lrow8];
    pa[p] = A + (size_t)(tk < 0 ? 0 : tk) * HDIM + gchunk * 8;
    pb[p] = Wt + ((size_t)e * HDIM + col0 + rb + lrow8) * HDIM + gchunk * 8;
  }

  floatx4 acc[4][4];
#pragma unroll
  for (int i = 0; i < 4; ++i)
#pragma unroll
    for (int j = 0; j < 4; ++j) acc[i][j] = (floatx4){0.f, 0.f, 0.f, 0.f};

  // prologue: stage tile 0 into buffer 0
#pragma unroll
  for (int p = 0; p < 4; ++p) {
    const int rb = wave * 8 + p * 32;
    gll16(pa[p], &As[rb * 64]);
    gll16(pb[p], &Bs[rb * 64]);
  }
  __syncthreads();

  int cur = 0;
  for (int t = 0; t < HDIM / 64; ++t) {
    const int nxt = cur ^ 1;
    if (t + 1 < HDIM / 64) {
      const int koff = (t + 1) * 64;
#pragma unroll
      for (int p = 0; p < 4; ++p) {
        const int rb = wave * 8 + p * 32;
        gll16(pa[p] + koff, &As[nxt * 8192 + rb * 64]);
        gll16(pb[p] + koff, &Bs[nxt * 8192 + rb * 64]);
      }
    }
    const __bf16* Ab = &As[cur * 8192];
    const __bf16* Bb = &Bs[cur * 8192];
#pragma unroll
    for (int kh = 0; kh < 2; ++kh) {
      bf16x8 a[4], b[4];
#pragma unroll
      for (int i = 0; i < 4; ++i)
        a[i] = *(const bf16x8*)&Ab[(wr + i * 16 + lrow) * 64 +
                                   (((kh * 4 + quad) ^ (lrow & 7)) * 8)];
#pragma unroll
      for (int j = 0; j < 4; ++j)
        b[j] = *(const bf16x8*)&Bb[(wc + j * 16 + lrow) * 64 +
                                   (((kh * 4 + quad) ^ (lrow & 7)) * 8)];
#pragma unroll
      for (int i = 0; i < 4; ++i)
#pragma unroll
        for (int j = 0; j < 4; ++j)
          acc[i][j] = __builtin_amdgcn_mfma_f32_16x16x32_bf16(a[i], b[j], acc[i][j], 0, 0, 0);
    }
    __syncthreads();   // drains vmcnt(0): stage of t+1 had 32 MFMAs of cover
    cur = nxt;
  }

  const float* be = Eb + (size_t)e * HDIM + col0;
#pragma unroll
  for (int i = 0; i < 4; ++i)
#pragma unroll
    for (int r = 0; r < 4; ++r) {
      const int row = wr + i * 16 + quad * 4 + r;
      const int tok = toks[row];
      if (tok < 0) continue;
      float* po = Out + (size_t)tok * HDIM + col0;
#pragma unroll
      for (int j = 0; j < 4; ++j) {
        const int col = wc + j * 16 + lrow;
        po[col] = acc[i][j][r] + be[col];
      }
    }
}

// ---------------------------------------------------------------------------
extern "C" void kernel_launch(void* const* d_in, const int* in_sizes, int n_in,
                              void* d_out, int out_size, void* d_ws, size_t ws_size,
                              hipStream_t stream) {
  (void)in_sizes; (void)n_in; (void)out_size; (void)ws_size;

  const float* hs = (const float*)d_in[0];
  const float* w1 = (const float*)d_in[1];
  const float* b1 = (const float*)d_in[2];
  const float* w2 = (const float*)d_in[3];
  const float* b2 = (const float*)d_in[4];
  const float* eW = (const float*)d_in[5];
  const float* eb = (const float*)d_in[6];
  float* out = (float*)d_out;

  // d_out doubles as scratch until expert_gemm_v6 (last kernel) overwrites it
  // completely: hfix [RCAP][MDIM] fp32 (8MB) + h_bf [NTOK][MDIM] bf16 (16MB).
  float* hfix = (float*)d_out;                                      // 8 MB @0
  __bf16* h_bf = (__bf16*)((char*)d_out + (size_t)8 * 1024 * 1024); // 16 MB

  char* wsb = (char*)d_ws;
  int* top_idx = (int*)wsb;                          // 65536 B
  int* ctrl    = (int*)(wsb + 65536);                // zeroed 128 B:
  int* counts  = ctrl;                               //   [0..7]
  int* risky_n = ctrl + 8;                           //   [8]
  int* cursor  = ctrl + 16;                          //   [16..23]
  int* risky   = (int*)(wsb + 65792);                // RCAP ints, 0xFF
  int* sorted  = risky + RCAP;                       // MAXCHUNK*CHUNK, 0xFF
  __bf16* hs_bf = (__bf16*)(wsb + 163840);           // 33.5 MB
  __bf16* w1t   = (__bf16*)(wsb + 163840 + 33554432);
  __bf16* eWt   = (__bf16*)(wsb + 163840 + 33554432 + 1048576);

  hipMemsetAsync(ctrl, 0, 128, stream);
  hipMemsetAsync(risky, 0xFF, (RCAP + MAXCHUNK * CHUNK) * sizeof(int), stream);

  cvt_hs<<<NTOK * HDIM / (256 * 8), 256, 0, stream>>>(hs, hs_bf);
  transpose_cvt<<<dim3(HDIM / 64, MDIM / 64, 1), 256, 0, stream>>>(w1, w1t, HDIM, MDIM);
  transpose_cvt<<<dim3(HDIM / 64, HDIM / 64, NEXP), 256, 0, stream>>>(eW, eWt, HDIM, HDIM);

  gemm1_h<<<dim3(G1_NWG), 256, 0, stream>>>(hs_bf, w1t, b1, h_bf);
  score_route<<<NTOK / 32, 256, 0, stream>>>(h_bf, w2, b2, top_idx, risky_n, risky);
  gemm1_fix_v2<<<dim3(MDIM / 64, RCAP / 32), 256, 0, stream>>>(hs, w1, b1, risky, hfix);
  rescore_fix<<<RCAP / 32, 256, 0, stream>>>(hfix, w2, b2, risky, top_idx);
  count_tokens<<<NTOK / 256, 256, 0, stream>>>(top_idx, counts);
  scatter_tokens<<<NTOK / 256, 256, 0, stream>>>(top_idx, counts, cursor, sorted);
  expert_gemm_v6<<<dim3(EG_NWG), 256, 0, stream>>>(hs_bf, eWt, eb, sorted, top_idx, out);
}

// Round 4
// 317.556 us; speedup vs baseline: 1.2052x; 1.0913x over previous
//
#include <hip/hip_runtime.h>

// Problem constants (B=4, S=4096 -> 16384 tokens; H=1024; M=H/2=512; E=8)
#define NTOK 16384
#define HDIM 1024
#define MDIM 512
#define NEXP 8
#define CHUNK 128
#define MAXCHUNK 136   // sum_e ceil(c_e/128) <= 135; +1 slack
#define RCAP 4096      // risky-token fixup list capacity (expect ~800)
#define DELTA 0.02f    // top2-gap guard >> bf16 score noise (~1e-3)
#define LSTR 72        // fp32->bf16 transpose LDS stride

#define G1_NWG ((MDIM / 128) * (NTOK / 128))   // 512, %8==0
#define EG_NWG (8 * MAXCHUNK)                  // 1088, %8==0

// prep kernel block-range partition
#define PREP_CVT 8192                       // NTOK*HDIM/(256*8)
#define PREP_W1 128                         // (HDIM/64)*(MDIM/64)
#define PREP_EW 2048                        // (HDIM/64)*(HDIM/64)*NEXP
#define PREP_TOTAL (PREP_CVT + PREP_W1 + PREP_EW + 1)

typedef __bf16 bf16x8 __attribute__((ext_vector_type(8)));
typedef float floatx4 __attribute__((ext_vector_type(4)));

// Async global->LDS 16B: LDS dest is wave-uniform base + lane*16 (HW-fixed).
__device__ __forceinline__ void gll16(const void* g, void* l) {
  __builtin_amdgcn_global_load_lds(
      (const __attribute__((address_space(1))) void*)g,
      (__attribute__((address_space(3))) void*)l, 16, 0, 0);
}

// ---------------------------------------------------------------------------
// Fused preprocessing: ONE dispatch replaces cvt_hs + transpose_cvt(w1) +
// transpose_cvt(eW) + 2 memsets. Branch on blockIdx.x range (uniform per
// block). Saves ~4 graph-node overheads (~10-15us each).
//   [0, 8192)           : hs fp32 -> bf16 (same layout)
//   [8192, 8320)        : w1 [H][M] -> w1t bf16 [M][H]
//   [8320, 10368)       : eW [e][H][H] -> eWt bf16 [e][Hcol][Hk]
//   [10368]             : ctrl zero + risky/sorted 0xFF init
// ---------------------------------------------------------------------------
__global__ __launch_bounds__(256) void prep(
    const float* __restrict__ hs, __bf16* __restrict__ hs_bf,
    const float* __restrict__ w1, __bf16* __restrict__ w1t,
    const float* __restrict__ eW, __bf16* __restrict__ eWt,
    int* __restrict__ ctrl, int* __restrict__ fillm1)
{
  __shared__ __align__(16) __bf16 T[64 * LSTR];
  const int bid = blockIdx.x;
  const int t = threadIdx.x;

  if (bid < PREP_CVT) {
    const size_t i = ((size_t)bid * 256 + t) * 8;
    float4 a = *(const float4*)&hs[i];
    float4 b = *(const float4*)&hs[i + 4];
    bf16x8 o;
    o[0] = (__bf16)a.x; o[1] = (__bf16)a.y; o[2] = (__bf16)a.z; o[3] = (__bf16)a.w;
    o[4] = (__bf16)b.x; o[5] = (__bf16)b.y; o[6] = (__bf16)b.z; o[7] = (__bf16)b.w;
    *(bf16x8*)&hs_bf[i] = o;
    return;
  }

  if (bid < PREP_CVT + PREP_W1 + PREP_EW) {
    int idx = bid - PREP_CVT;
    const float* S; __bf16* D; int K, C, k0, c0;
    if (idx < PREP_W1) {
      K = HDIM; C = MDIM;
      k0 = (idx & 15) * 64; c0 = (idx >> 4) * 64;
      S = w1; D = w1t;
    } else {
      idx -= PREP_W1;
      K = HDIM; C = HDIM;
      const int b = idx >> 8, r = idx & 255;
      k0 = (r & 15) * 64; c0 = (r >> 4) * 64;
      S = eW + (size_t)b * K * C; D = eWt + (size_t)b * K * C;
    }
    {
      const int rr = t >> 2, cc = (t & 3) * 16;
      const float* p = S + (size_t)(k0 + rr) * C + c0 + cc;
      float4 v0 = *(const float4*)&p[0];
      float4 v1 = *(const float4*)&p[4];
      float4 v2 = *(const float4*)&p[8];
      float4 v3 = *(const float4*)&p[12];
      float vv[16] = {v0.x, v0.y, v0.z, v0.w, v1.x, v1.y, v1.z, v1.w,
                      v2.x, v2.y, v2.z, v2.w, v3.x, v3.y, v3.z, v3.w};
#pragma unroll
      for (int j = 0; j < 16; ++j) T[(cc + j) * LSTR + rr] = (__bf16)vv[j];
    }
    __syncthreads();
    {
      const int c = t >> 2, kk = (t & 3) * 16;
      __bf16* q = D + (size_t)(c0 + c) * K + k0 + kk;
      *(float4*)&q[0] = *(const float4*)&T[c * LSTR + kk];
      *(float4*)&q[8] = *(const float4*)&T[c * LSTR + kk + 8];
    }
    return;
  }

  // workspace init block: ctrl[0..31]=0; risky+sorted = -1
  if (t < 32) ctrl[t] = 0;
  const int n = RCAP + MAXCHUNK * CHUNK;
  for (int i = t; i < n; i += 256) fillm1[i] = -1;
}

// ---------------------------------------------------------------------------
// GEMM1 + fused routing-score partials (R1-verified: 326us total config).
// 128x128 tile, BK=64, 2-phase double-buffered global_load_lds staging,
// XOR k-chunk swizzle, XCD-bijective row-major-grouped block swizzle.
// Epilogue computes s_part[colblk][t][e] = sum_cols relu(h)*w2 — no h output.
// ---------------------------------------------------------------------------
__global__ __launch_bounds__(256) void gemm1_score(
    const __bf16* __restrict__ A,    // hs_bf16 [NTOK][HDIM]
    const __bf16* __restrict__ Bt,   // w1t [MDIM][HDIM]
    const float* __restrict__ bias,  // b1 [MDIM]
    const float* __restrict__ w2,    // [MDIM][8]
    float* __restrict__ scores_part) // [4][NTOK][8]
{
  __shared__ __align__(16) __bf16 As[2 * 128 * 64];
  __shared__ __align__(16) __bf16 Bs[2 * 128 * 64];

  const int tid = threadIdx.x;
  const int swz = (blockIdx.x & 7) * (G1_NWG / 8) + (blockIdx.x >> 3);
  const int rowBlk = swz >> 2;          // 0..127
  const int cb = swz & 3;               // 0..3
  const int row0 = rowBlk * 128, col0 = cb * 128;
  const int wave = tid >> 6, lane = tid & 63;
  const int lrow8 = lane >> 3;
  const int gchunk = (lane & 7) ^ lrow8;   // global-side swizzle
  const int wr = (wave >> 1) * 64, wc = (wave & 1) * 64;
  const int lrow = lane & 15, quad = lane >> 4;

  const __bf16 *pa[4], *pb[4];
#pragma unroll
  for (int p = 0; p < 4; ++p) {
    const int rb = wave * 8 + p * 32;   // 8-aligned -> row&7 == lrow8
    pa[p] = A + (size_t)(row0 + rb + lrow8) * HDIM + gchunk * 8;
    pb[p] = Bt + (size_t)(col0 + rb + lrow8) * HDIM + gchunk * 8;
  }

  floatx4 acc[4][4];
#pragma unroll
  for (int i = 0; i < 4; ++i)
#pragma unroll
    for (int j = 0; j < 4; ++j) acc[i][j] = (floatx4){0.f, 0.f, 0.f, 0.f};

  // prologue: stage tile 0 into buffer 0
#pragma unroll
  for (int p = 0; p < 4; ++p) {
    const int rb = wave * 8 + p * 32;
    gll16(pa[p], &As[rb * 64]);
    gll16(pb[p], &Bs[rb * 64]);
  }
  __syncthreads();

  int cur = 0;
  for (int t = 0; t < HDIM / 64; ++t) {
    const int nxt = cur ^ 1;
    if (t + 1 < HDIM / 64) {
      const int koff = (t + 1) * 64;
#pragma unroll
      for (int p = 0; p < 4; ++p) {
        const int rb = wave * 8 + p * 32;
        gll16(pa[p] + koff, &As[nxt * 8192 + rb * 64]);
        gll16(pb[p] + koff, &Bs[nxt * 8192 + rb * 64]);
      }
    }
    const __bf16* Ab = &As[cur * 8192];
    const __bf16* Bb = &Bs[cur * 8192];
#pragma unroll
    for (int kh = 0; kh < 2; ++kh) {
      bf16x8 a[4], b[4];
#pragma unroll
      for (int i = 0; i < 4; ++i)
        a[i] = *(const bf16x8*)&Ab[(wr + i * 16 + lrow) * 64 +
                                   (((kh * 4 + quad) ^ (lrow & 7)) * 8)];
#pragma unroll
      for (int j = 0; j < 4; ++j)
        b[j] = *(const bf16x8*)&Bb[(wc + j * 16 + lrow) * 64 +
                                   (((kh * 4 + quad) ^ (lrow & 7)) * 8)];
#pragma unroll
      for (int i = 0; i < 4; ++i)
#pragma unroll
        for (int j = 0; j < 4; ++j)
          acc[i][j] = __builtin_amdgcn_mfma_f32_16x16x32_bf16(a[i], b[j], acc[i][j], 0, 0, 0);
    }
    __syncthreads();   // drains vmcnt(0): stage of t+1 had 32 MFMAs of cover
    cur = nxt;
  }

  // ---- fused scoring epilogue (reuses As/Bs LDS) ----
  float* w2s = (float*)As;    // 4KB: w2 cols col0..col0+127
  float* sblk = (float*)Bs;   // 8KB: [2 wc-halves][128 rows][8]
  *(float4*)&w2s[tid * 4] = *(const float4*)&w2[col0 * 8 + tid * 4];
  __syncthreads();

  float bj[4];
  float4 wja[4], wjb[4];
#pragma unroll
  for (int j = 0; j < 4; ++j) {
    const int cl = wc + j * 16 + lrow;
    bj[j] = bias[col0 + cl];
    wja[j] = *(const float4*)&w2s[cl * 8];
    wjb[j] = *(const float4*)&w2s[cl * 8 + 4];
  }

#pragma unroll
  for (int i = 0; i < 4; ++i) {
#pragma unroll
    for (int r = 0; r < 4; ++r) {
      float4 sA = {0, 0, 0, 0}, sB = {0, 0, 0, 0};
#pragma unroll
      for (int j = 0; j < 4; ++j) {
        float h = fmaxf(acc[i][j][r] + bj[j], 0.f);
        sA.x += h * wja[j].x; sA.y += h * wja[j].y;
        sA.z += h * wja[j].z; sA.w += h * wja[j].w;
        sB.x += h * wjb[j].x; sB.y += h * wjb[j].y;
        sB.z += h * wjb[j].z; sB.w += h * wjb[j].w;
      }
#pragma unroll
      for (int m = 1; m <= 8; m <<= 1) {
        sA.x += __shfl_xor(sA.x, m, 64); sA.y += __shfl_xor(sA.y, m, 64);
        sA.z += __shfl_xor(sA.z, m, 64); sA.w += __shfl_xor(sA.w, m, 64);
        sB.x += __shfl_xor(sB.x, m, 64); sB.y += __shfl_xor(sB.y, m, 64);
        sB.z += __shfl_xor(sB.z, m, 64); sB.w += __shfl_xor(sB.w, m, 64);
      }
      if (lrow == 0) {
        const int rloc = wr + i * 16 + quad * 4 + r;  // unique writer per slot
        *(float4*)&sblk[((wave & 1) * 128 + rloc) * 8] = sA;
        *(float4*)&sblk[((wave & 1) * 128 + rloc) * 8 + 4] = sB;
      }
    }
  }
  __syncthreads();
  {
    const int r = tid >> 1, e4 = (tid & 1) * 4;
    float4 v0 = *(const float4*)&sblk[r * 8 + e4];
    float4 v1 = *(const float4*)&sblk[(128 + r) * 8 + e4];
    float4 o = {v0.x + v1.x, v0.y + v1.y, v0.z + v1.z, v0.w + v1.w};
    *(float4*)&scores_part[((size_t)cb * NTOK + row0 + r) * 8 + e4] = o;
  }
}

// ---------------------------------------------------------------------------
// Sum 4 col-block partials, +b2, argmax; flag near-ties (gap < DELTA);
// PROVISIONAL per-expert counts (rescore_fix adjusts flips atomically).
// ---------------------------------------------------------------------------
__global__ __launch_bounds__(256) void routing_argmax(
    const float* __restrict__ scores_part, const float* __restrict__ b2,
    int* __restrict__ top_idx, int* __restrict__ risky_n,
    int* __restrict__ risky, int* __restrict__ counts)
{
  __shared__ int rbuf[256];
  __shared__ int lc[NEXP];
  __shared__ int rcnt, rbase;
  if (threadIdx.x == 0) rcnt = 0;
  if (threadIdx.x < NEXP) lc[threadIdx.x] = 0;
  __syncthreads();

  const int t = blockIdx.x * 256 + threadIdx.x;
  float4 sa = {0, 0, 0, 0}, sb = {0, 0, 0, 0};
#pragma unroll
  for (int c = 0; c < 4; ++c) {
    float4 va = *(const float4*)&scores_part[((size_t)c * NTOK + t) * 8];
    float4 vb = *(const float4*)&scores_part[((size_t)c * NTOK + t) * 8 + 4];
    sa.x += va.x; sa.y += va.y; sa.z += va.z; sa.w += va.w;
    sb.x += vb.x; sb.y += vb.y; sb.z += vb.z; sb.w += vb.w;
  }
  float s[8] = {sa.x + b2[0], sa.y + b2[1], sa.z + b2[2], sa.w + b2[3],
                sb.x + b2[4], sb.y + b2[5], sb.z + b2[6], sb.w + b2[7]};
  float best = s[0], second = -1e30f;
  int bi = 0;
#pragma unroll
  for (int e = 1; e < 8; ++e) {
    if (s[e] > best) { second = best; best = s[e]; bi = e; }
    else if (s[e] > second) second = s[e];
  }
  top_idx[t] = bi;
  atomicAdd(&lc[bi], 1);
  if (best - second < DELTA) rbuf[atomicAdd(&rcnt, 1)] = t;
  __syncthreads();
  if (threadIdx.x == 0 && rcnt > 0) rbase = atomicAdd(risky_n, rcnt);
  if (threadIdx.x < NEXP) atomicAdd(&counts[threadIdx.x], lc[threadIdx.x]);
  __syncthreads();
  if ((int)threadIdx.x < rcnt) {
    int slot = rbase + threadIdx.x;
    if (slot < RCAP) risky[slot] = rbuf[threadIdx.x];
  }
}

// ---------------------------------------------------------------------------
// Exact fp32 h for risky tokens -> compact hfix[RCAP][MDIM].
// ---------------------------------------------------------------------------
__global__ __launch_bounds__(256) void gemm1_fix_v2(
    const float* __restrict__ A, const float* __restrict__ W,
    const float* __restrict__ bias, const int* __restrict__ risky,
    float* __restrict__ hfix)
{
  __shared__ float As[32][33];
  __shared__ float Bs[32][64];
  __shared__ int toks[32];

  const int tid = threadIdx.x;
  if (tid < 32) toks[tid] = risky[blockIdx.y * 32 + tid];
  __syncthreads();
  if (toks[0] < 0) return;

  const int col0 = blockIdx.x * 64;
  const int tx = tid & 15, ty = tid >> 4;
  float acc0[4] = {0, 0, 0, 0}, acc1[4] = {0, 0, 0, 0};

  const int sr = tid >> 3;
  const int lo = tid & 7;
  const int sc8 = lo * 8;
  const int tokS = toks[sr];
  const float* pa = (tokS >= 0) ? A + (size_t)tokS * HDIM : A;

  for (int k0 = 0; k0 < HDIM; k0 += 32) {
    float4 av = make_float4(0, 0, 0, 0);
    if (tokS >= 0) av = *(const float4*)&pa[k0 + (lo & 3) * 4 + (lo >> 2) * 16];
    float4 b0 = *(const float4*)&W[(size_t)(k0 + sr) * MDIM + col0 + sc8];
    float4 b1v = *(const float4*)&W[(size_t)(k0 + sr) * MDIM + col0 + sc8 + 4];
    const int kk = (lo & 3) * 4 + (lo >> 2) * 16;
    As[kk + 0][sr] = av.x; As[kk + 1][sr] = av.y;
    As[kk + 2][sr] = av.z; As[kk + 3][sr] = av.w;
    *(float4*)&Bs[sr][sc8] = b0;
    *(float4*)&Bs[sr][sc8 + 4] = b1v;
    __syncthreads();

#pragma unroll
    for (int k = 0; k < 32; ++k) {
      float a0 = As[k][ty], a1 = As[k][ty + 16];
      float4 bv = *(const float4*)&Bs[k][tx * 4];
      acc0[0] = fmaf(a0, bv.x, acc0[0]); acc0[1] = fmaf(a0, bv.y, acc0[1]);
      acc0[2] = fmaf(a0, bv.z, acc0[2]); acc0[3] = fmaf(a0, bv.w, acc0[3]);
      acc1[0] = fmaf(a1, bv.x, acc1[0]); acc1[1] = fmaf(a1, bv.y, acc1[1]);
      acc1[2] = fmaf(a1, bv.z, acc1[2]); acc1[3] = fmaf(a1, bv.w, acc1[3]);
    }
    __syncthreads();
  }

  const int c = col0 + tx * 4;
  const int i0 = blockIdx.y * 32 + ty, i1 = blockIdx.y * 32 + ty + 16;
  if (toks[ty] >= 0) {
    float4 v;
    v.x = fmaxf(acc0[0] + bias[c + 0], 0.f); v.y = fmaxf(acc0[1] + bias[c + 1], 0.f);
    v.z = fmaxf(acc0[2] + bias[c + 2], 0.f); v.w = fmaxf(acc0[3] + bias[c + 3], 0.f);
    *(float4*)&hfix[(size_t)i0 * MDIM + c] = v;
  }
  if (toks[ty + 16] >= 0) {
    float4 v;
    v.x = fmaxf(acc1[0] + bias[c + 0], 0.f); v.y = fmaxf(acc1[1] + bias[c + 1], 0.f);
    v.z = fmaxf(acc1[2] + bias[c + 2], 0.f); v.w = fmaxf(acc1[3] + bias[c + 3], 0.f);
    *(float4*)&hfix[(size_t)i1 * MDIM + c] = v;
  }
}

// ---------------------------------------------------------------------------
// Exact rescore of risky tokens from hfix; overwrite top_idx + adjust counts.
// ---------------------------------------------------------------------------
__global__ __launch_bounds__(256) void rescore_fix(
    const float* __restrict__ hfix, const float* __restrict__ w2,
    const float* __restrict__ b2, const int* __restrict__ risky,
    int* __restrict__ top_idx, int* __restrict__ counts)
{
  const int idx = blockIdx.x * 32 + (threadIdx.x >> 3);
  const int l8 = threadIdx.x & 7;
  const int t = risky[idx];

  float s[8] = {0, 0, 0, 0, 0, 0, 0, 0};
  if (t >= 0) {
    const float* hrow = hfix + (size_t)idx * MDIM;
    for (int k = l8; k < MDIM; k += 8) {
      float hv = hrow[k];
      float4 wa = *(const float4*)&w2[k * 8];
      float4 wb = *(const float4*)&w2[k * 8 + 4];
      s[0] += hv * wa.x; s[1] += hv * wa.y; s[2] += hv * wa.z; s[3] += hv * wa.w;
      s[4] += hv * wb.x; s[5] += hv * wb.y; s[6] += hv * wb.z; s[7] += hv * wb.w;
    }
  }
#pragma unroll
  for (int off = 4; off > 0; off >>= 1)
#pragma unroll
    for (int e = 0; e < 8; ++e) s[e] += __shfl_xor(s[e], off, 64);

  if (l8 == 0 && t >= 0) {
    float best = s[0] + b2[0];
    int bi = 0;
#pragma unroll
    for (int e = 1; e < 8; ++e) {
      float v = s[e] + b2[e];
      if (v > best) { best = v; bi = e; }
    }
    const int old = top_idx[t];
    if (bi != old) {
      top_idx[t] = bi;
      atomicSub(&counts[old], 1);
      atomicAdd(&counts[bi], 1);
    }
  }
}

// Scatter with inline padded-offset prefix (counts final after rescore_fix).
__global__ __launch_bounds__(256) void scatter_tokens(
    const int* __restrict__ top_idx, const int* __restrict__ counts,
    int* __restrict__ cursor, int* __restrict__ sorted)
{
  __shared__ int lc[NEXP], lbase[NEXP], off_s[NEXP];
  if (threadIdx.x < NEXP) lc[threadIdx.x] = 0;
  if (threadIdx.x == 0) {
    int off = 0;
    for (int e = 0; e < NEXP; ++e) {
      off_s[e] = off;
      off += ((counts[e] + CHUNK - 1) / CHUNK) * CHUNK;
    }
  }
  __syncthreads();
  const int t = blockIdx.x * 256 + threadIdx.x;
  const int e = top_idx[t];
  const int r = atomicAdd(&lc[e], 1);
  __syncthreads();
  if (threadIdx.x < NEXP)
    lbase[threadIdx.x] = atomicAdd(&cursor[threadIdx.x], lc[threadIdx.x]);
  __syncthreads();
  sorted[off_s[e] + lbase[e] + r] = t;
}

// ---------------------------------------------------------------------------
// Expert GEMM v6 (measured-best structure, unchanged): 128x128 tile, BK=64,
// 256 thr, 2-phase double-buffered global_load_lds staging, XOR k-chunk
// swizzle, XCD chunk-major block swizzle (weights L2-resident/XCD).
// ---------------------------------------------------------------------------
__global__ __launch_bounds__(256) void expert_gemm_v6(
    const __bf16* __restrict__ A,   // hs_bf16 [NTOK][HDIM]
    const __bf16* __restrict__ Wt,  // [NEXP][HDIM(col)][HDIM(k)]
    const float* __restrict__ Eb,   // [NEXP][HDIM]
    const int* __restrict__ sorted,
    const int* __restrict__ top_idx,
    float* __restrict__ Out)
{
  __shared__ __align__(16) __bf16 As[2 * 128 * 64];
  __shared__ __align__(16) __bf16 Bs[2 * 128 * 64];
  __shared__ int toks[CHUNK];

  const int tid = threadIdx.x;
  const int swz = (blockIdx.x & 7) * (EG_NWG / 8) + (blockIdx.x >> 3);
  const int chunkIdx = swz >> 3;   // 0..135
  const int cb = swz & 7;          // 0..7
  if (tid < CHUNK) toks[tid] = sorted[(size_t)chunkIdx * CHUNK + tid];
  __syncthreads();
  if (toks[0] < 0) return;

  const int e = top_idx[toks[0]];
  const int col0 = cb * 128;
  const int wave = tid >> 6, lane = tid & 63;
  const int lrow8 = lane >> 3;
  const int gchunk = (lane & 7) ^ lrow8;
  const int wr = (wave >> 1) * 64, wc = (wave & 1) * 64;
  const int lrow = lane & 15, quad = lane >> 4;

  const __bf16 *pa[4], *pb[4];
#pragma unroll
  for (int p = 0; p < 4; ++p) {
    const int rb = wave * 8 + p * 32;
    const int tk = toks[rb + lrow8];
    pa[p] = A + (size_t)(tk < 0 ? 0 : tk) * HDIM + gchunk * 8;
    pb[p] = Wt + ((size_t)e * HDIM + col0 + rb + lrow8) * HDIM + gchunk * 8;
  }

  floatx4 acc[4][4];
#pragma unroll
  for (int i = 0; i < 4; ++i)
#pragma unroll
    for (int j = 0; j < 4; ++j) acc[i][j] = (floatx4){0.f, 0.f, 0.f, 0.f};

  // prologue: stage tile 0 into buffer 0
#pragma unroll
  for (int p = 0; p < 4; ++p) {
    const int rb = wave * 8 + p * 32;
    gll16(pa[p], &As[rb * 64]);
    gll16(pb[p], &Bs[rb * 64]);
  }
  __syncthreads();

  int cur = 0;
  for (int t = 0; t < HDIM / 64; ++t) {
    const int nxt = cur ^ 1;
    if (t + 1 < HDIM / 64) {
      const int koff = (t + 1) * 64;
#pragma unroll
      for (int p = 0; p < 4; ++p) {
        const int rb = wave * 8 + p * 32;
        gll16(pa[p] + koff, &As[nxt * 8192 + rb * 64]);
        gll16(pb[p] + koff, &Bs[nxt * 8192 + rb * 64]);
      }
    }
    const __bf16* Ab = &As[cur * 8192];
    const __bf16* Bb = &Bs[cur * 8192];
#pragma unroll
    for (int kh = 0; kh < 2; ++kh) {
      bf16x8 a[4], b[4];
#pragma unroll
      for (int i = 0; i < 4; ++i)
        a[i] = *(const bf16x8*)&Ab[(wr + i * 16 + lrow) * 64 +
                                   (((kh * 4 + quad) ^ (lrow & 7)) * 8)];
#pragma unroll
      for (int j = 0; j < 4; ++j)
        b[j] = *(const bf16x8*)&Bb[(wc + j * 16 + lrow) * 64 +
                                   (((kh * 4 + quad) ^ (lrow & 7)) * 8)];
#pragma unroll
      for (int i = 0; i < 4; ++i)
#pragma unroll
        for (int j = 0; j < 4; ++j)
          acc[i][j] = __builtin_amdgcn_mfma_f32_16x16x32_bf16(a[i], b[j], acc[i][j], 0, 0, 0);
    }
    __syncthreads();   // drains vmcnt(0): stage of t+1 had 32 MFMAs of cover
    cur = nxt;
  }

  const float* be = Eb + (size_t)e * HDIM + col0;
#pragma unroll
  for (int i = 0; i < 4; ++i)
#pragma unroll
    for (int r = 0; r < 4; ++r) {
      const int row = wr + i * 16 + quad * 4 + r;
      const int tok = toks[row];
      if (tok < 0) continue;
      float* po = Out + (size_t)tok * HDIM + col0;
#pragma unroll
      for (int j = 0; j < 4; ++j) {
        const int col = wc + j * 16 + lrow;
        po[col] = acc[i][j][r] + be[col];
      }
    }
}

// ---------------------------------------------------------------------------
extern "C" void kernel_launch(void* const* d_in, const int* in_sizes, int n_in,
                              void* d_out, int out_size, void* d_ws, size_t ws_size,
                              hipStream_t stream) {
  (void)in_sizes; (void)n_in; (void)out_size; (void)ws_size;

  const float* hs = (const float*)d_in[0];
  const float* w1 = (const float*)d_in[1];
  const float* b1 = (const float*)d_in[2];
  const float* w2 = (const float*)d_in[3];
  const float* b2 = (const float*)d_in[4];
  const float* eW = (const float*)d_in[5];
  const float* eb = (const float*)d_in[6];
  float* out = (float*)d_out;

  // d_out doubles as scratch until expert_gemm_v6 (the last kernel)
  // overwrites it completely: hfix [RCAP][MDIM] + scores_part [4][NTOK][8].
  float* hfix = (float*)d_out;                       // 8 MB
  float* scores_part = hfix + (size_t)RCAP * MDIM;   // 2 MB

  char* wsb = (char*)d_ws;
  int* top_idx = (int*)wsb;                          // 65536 B
  int* ctrl    = (int*)(wsb + 65536);                // zeroed (by prep) 128 B:
  int* counts  = ctrl;                               //   [0..7]
  int* risky_n = ctrl + 8;                           //   [8]
  int* cursor  = ctrl + 16;                          //   [16..23]
  int* risky   = (int*)(wsb + 65792);                // RCAP ints, -1 (by prep)
  int* sorted  = risky + RCAP;                       // MAXCHUNK*CHUNK, -1
  __bf16* hs_bf = (__bf16*)(wsb + 163840);           // 33.5 MB
  __bf16* w1t   = (__bf16*)(wsb + 163840 + 33554432);
  __bf16* eWt   = (__bf16*)(wsb + 163840 + 33554432 + 1048576);

  prep<<<PREP_TOTAL, 256, 0, stream>>>(hs, hs_bf, w1, w1t, eW, eWt, ctrl, risky);
  gemm1_score<<<dim3(G1_NWG), 256, 0, stream>>>(hs_bf, w1t, b1, w2, scores_part);
  routing_argmax<<<NTOK / 256, 256, 0, stream>>>(scores_part, b2, top_idx, risky_n, risky, counts);
  gemm1_fix_v2<<<dim3(MDIM / 64, RCAP / 32), 256, 0, stream>>>(hs, w1, b1, risky, hfix);
  rescore_fix<<<RCAP / 32, 256, 0, stream>>>(hfix, w2, b2, risky, top_idx, counts);
  scatter_tokens<<<NTOK / 256, 256, 0, stream>>>(top_idx, counts, cursor, sorted);
  expert_gemm_v6<<<dim3(EG_NWG), 256, 0, stream>>>(hs_bf, eWt, eb, sorted, top_idx, out);
}